// Round 2
// baseline (1260.259 us; speedup 1.0000x reference)
//
#include <hip/hip_runtime.h>
#include <hip/hip_fp16.h>

#define B_    256
#define CIN   128
#define CH    64
#define NPX   1024   // 32*32
#define NWIN  49
#define HALO  22     // 16 tile rows + 3 halo each side
#define TCOLS 40     // 32 cols + 4 halo each side
#define CG    8      // channels per LDS group
#define NEG_INF_F (-1e30f)

// ---------------------------------------------------------------------------
// Transpose W (Ch x Cin -> Cin x Ch); resolve same_WqWk on device.
// ---------------------------------------------------------------------------
__global__ __launch_bounds__(256) void wtrans_kernel(
    const float* __restrict__ Wq, const float* __restrict__ Wk,
    const int* __restrict__ same_flag,
    float* __restrict__ WtQ, float* __restrict__ WtK)
{
    const float* Wsel = (same_flag[0] != 0) ? Wq : Wk;
    for (int idx = threadIdx.x; idx < CH * CIN; idx += 256) {
        int i = idx >> 6;
        int o = idx & 63;
        WtQ[idx] = Wq[o * CIN + i];
        WtK[idx] = Wsel[o * CIN + i];
    }
}

// ---------------------------------------------------------------------------
// 1x1 conv: dst[b,o,p] = sum_i Wt[i,o]*x[b,i,p] + bias[o], output f16.
// launch_bounds(256,2) -> 128 VGPR budget so acc[64] stays in registers.
// ---------------------------------------------------------------------------
__global__ __launch_bounds__(256, 2) void conv_kernel(
    const float* __restrict__ x, const float* __restrict__ Wt,
    const float* __restrict__ bias_a, const float* __restrict__ bias_b,
    const int* __restrict__ sel_flag,
    __half* __restrict__ dst)
{
    const float* bias = (sel_flag != nullptr && sel_flag[0] != 0) ? bias_b : bias_a;
    int b  = blockIdx.x >> 2;
    int px = ((blockIdx.x & 3) << 8) + threadIdx.x;

    const float* xb = x + (size_t)b * (CIN * NPX) + px;
    float acc[CH];
#pragma unroll
    for (int o = 0; o < CH; ++o) acc[o] = bias[o];

#pragma unroll 4
    for (int i = 0; i < CIN; ++i) {
        float xv = xb[(size_t)i * NPX];
        const float* wrow = Wt + (i << 6);
#pragma unroll
        for (int o = 0; o < CH; ++o) acc[o] = fmaf(wrow[o], xv, acc[o]);
    }

    __half* db = dst + (size_t)b * (CH * NPX) + px;
#pragma unroll
    for (int o = 0; o < CH; ++o) db[(size_t)o << 10] = __float2half(acc[o]);
}

// pick half (i) out of a packed __half2 array, i compile-time constant
#define PW(arr, i) __half2float(((i) & 1) ? __high2half(arr[(i) >> 1]) : __low2half(arr[(i) >> 1]))

// ---------------------------------------------------------------------------
// Fused local attention, one 16-row tile per block, 2 vertical px per thread.
// LDS tile [22 rows][40 cols][8 ch] f16 (14 KB), zero-filled borders once.
// Phase A: scores f32[49] x 2px via v_fma_mix (f16 K * f16->f32 Q).
// Phase B: masked softmax, weights repacked to __half2 (register relief).
// Phase C: same tile layout for V (f32->f16 on stage), f32 accumulate.
// ---------------------------------------------------------------------------
__global__ __launch_bounds__(256, 2) void attend_kernel(
    const __half* __restrict__ Q, const __half* __restrict__ K,
    const float* __restrict__ V,          // raw key-side features, CIN ch
    float* __restrict__ out,              // (B,256,32,32) f32
    int chan_base,
    const float* __restrict__ copy_src,   // left features (self_attend==0)
    const int* __restrict__ self_flag)
{
    __shared__ __align__(16) __half buf[HALO * TCOLS * CG];   // 14080 B

    int b    = blockIdx.x >> 1;
    int tile = blockIdx.x & 1;
    int h0   = tile << 4;
    int t    = threadIdx.x;
    int w    = t & 31;
    int r2   = (t >> 5) << 1;     // 0,2,..,14
    int h    = h0 + r2;           // this thread: rows h and h+1

    if (copy_src != nullptr && self_flag[0] == 0) {
        const float* s = copy_src + (size_t)b * (CIN * NPX) + (h << 5) + w;
        float* d = out + (size_t)b * (2 * CIN * NPX) + ((size_t)chan_base << 10) + (h << 5) + w;
        for (int c = 0; c < CIN; ++c) {
            d[(size_t)c << 10] = s[(size_t)c << 10];
            d[((size_t)c << 10) + 32] = s[((size_t)c << 10) + 32];
        }
        return;
    }

    // ---- zero-fill LDS once (borders stay 0 across all groups) ----
    int* ibuf = (int*)buf;
#pragma unroll
    for (int i = 0; i < 14; ++i) {
        int idx = t + (i << 8);
        if (idx < HALO * TCOLS * CG / 2) ibuf[idx] = 0;
    }

    // ---- staging geometry (shift-only; no divisions) ----
    // 19 valid rows x 32 cols x 8 ch = 4864 elems = 256 thr x 19 iters.
    int rowlo = (h0 == 0) ? 0 : h0 - 3;       // first valid global row
    int rowof = (h0 == 0) ? 3 : 0;            // its LDS row index
    int sc_c  = (t >> 5) & 7;                 // this thread's channel
    int sc_gc = t & 31;                       // this thread's column
    int go_base = (sc_c << 10) + (rowlo << 5) + sc_gc;
    int li_base = (rowof * TCOLS + sc_gc + 4) * CG + sc_c;
    int tap0 = (r2 * TCOLS + w + 1) * CG;     // LDS half-index of (wr=0,dw=0)

    const __half* Kb = K + (size_t)b * (CH * NPX);
    const __half* Qb = Q + (size_t)b * (CH * NPX);
    int qoff = (h << 5) + w;

    float sc0[NWIN], sc1[NWIN];
#pragma unroll
    for (int i = 0; i < NWIN; ++i) { sc0[i] = 0.f; sc1[i] = 0.f; }

    // ---- Phase A: scores over 64 channels, 8 per group ----
    for (int cg = 0; cg < CH / CG; ++cg) {
        __syncthreads();
        {
            const __half* Ks = Kb + ((size_t)(cg * CG) << 10);
            int go = go_base, li = li_base;
#pragma unroll
            for (int i = 0; i < 19; ++i) {
                buf[li] = Ks[go];
                go += 32; li += TCOLS * CG;
            }
        }
        __syncthreads();

        float qa[CG], qc[CG];
#pragma unroll
        for (int c = 0; c < CG; ++c) {
            const __half* qp = Qb + (((size_t)(cg * CG + c)) << 10) + qoff;
            qa[c] = __half2float(qp[0]);
            qc[c] = __half2float(qp[32]);
        }
#pragma unroll
        for (int wr = 0; wr < 8; ++wr) {
#pragma unroll
            for (int dw = 0; dw < 7; ++dw) {
                union { int4 v; __half hh[8]; } kk;
                kk.v = *(const int4*)(buf + tap0 + (wr * TCOLS + dw) * CG);
                if (wr < 7) {
                    float s = sc0[wr * 7 + dw];
#pragma unroll
                    for (int c = 0; c < CG; ++c) s = fmaf(__half2float(kk.hh[c]), qa[c], s);
                    sc0[wr * 7 + dw] = s;
                }
                if (wr >= 1) {
                    float s = sc1[(wr - 1) * 7 + dw];
#pragma unroll
                    for (int c = 0; c < CG; ++c) s = fmaf(__half2float(kk.hh[c]), qc[c], s);
                    sc1[(wr - 1) * 7 + dw] = s;
                }
            }
        }
    }

    // ---- Phase B: masked softmax per pixel, repack weights to half2 ----
    __half2 ph0[25], ph1[25];
    {
        float m0 = NEG_INF_F, m1 = NEG_INF_F;
#pragma unroll
        for (int dh = 0; dh < 7; ++dh) {
#pragma unroll
            for (int dw = 0; dw < 7; ++dw) {
                int i = dh * 7 + dw;
                bool cok = ((unsigned)(w + dw - 3) < 32u);
                bool v0 = ((unsigned)(h + dh - 3) < 32u) && cok;
                bool v1 = ((unsigned)(h + 1 + dh - 3) < 32u) && cok;
                sc0[i] = v0 ? sc0[i] : NEG_INF_F;
                sc1[i] = v1 ? sc1[i] : NEG_INF_F;
                m0 = fmaxf(m0, sc0[i]);
                m1 = fmaxf(m1, sc1[i]);
            }
        }
        float s0 = 0.f, s1 = 0.f;
#pragma unroll
        for (int i = 0; i < NWIN; ++i) {
            sc0[i] = __expf(sc0[i] - m0); s0 += sc0[i];
            sc1[i] = __expf(sc1[i] - m1); s1 += sc1[i];
        }
        float i0 = 1.f / s0, i1 = 1.f / s1;
#pragma unroll
        for (int j = 0; j < 24; ++j) {
            ph0[j] = __halves2half2(__float2half(sc0[2 * j] * i0), __float2half(sc0[2 * j + 1] * i0));
            ph1[j] = __halves2half2(__float2half(sc1[2 * j] * i1), __float2half(sc1[2 * j + 1] * i1));
        }
        ph0[24] = __halves2half2(__float2half(sc0[48] * i0), __float2half(0.f));
        ph1[24] = __halves2half2(__float2half(sc1[48] * i1), __float2half(0.f));
    }

    // ---- Phase C: weighted V sum, 8 channels per group ----
    const float* Vb = V + (size_t)b * (CIN * NPX);
    float* ob = out + (size_t)b * (2 * CIN * NPX) + ((size_t)chan_base << 10) + qoff;

    for (int vg = 0; vg < CIN / CG; ++vg) {
        __syncthreads();
        {
            const float* Vs = Vb + ((size_t)(vg * CG) << 10);
            int go = go_base, li = li_base;
#pragma unroll
            for (int i = 0; i < 19; ++i) {
                buf[li] = __float2half(Vs[go]);
                go += 32; li += TCOLS * CG;
            }
        }
        __syncthreads();

        float a0[CG], a1[CG];
#pragma unroll
        for (int c = 0; c < CG; ++c) { a0[c] = 0.f; a1[c] = 0.f; }
#pragma unroll
        for (int wr = 0; wr < 8; ++wr) {
#pragma unroll
            for (int dw = 0; dw < 7; ++dw) {
                union { int4 v; __half hh[8]; } vv;
                vv.v = *(const int4*)(buf + tap0 + (wr * TCOLS + dw) * CG);
                if (wr < 7) {
                    float p = PW(ph0, wr * 7 + dw);
#pragma unroll
                    for (int c = 0; c < CG; ++c) a0[c] = fmaf(__half2float(vv.hh[c]), p, a0[c]);
                }
                if (wr >= 1) {
                    float p = PW(ph1, (wr - 1) * 7 + dw);
#pragma unroll
                    for (int c = 0; c < CG; ++c) a1[c] = fmaf(__half2float(vv.hh[c]), p, a1[c]);
                }
            }
        }
#pragma unroll
        for (int c = 0; c < CG; ++c) {
            ob[((size_t)(vg * CG + c)) << 10] = a0[c];
            ob[(((size_t)(vg * CG + c)) << 10) + 32] = a1[c];
        }
    }
}

// ---------------------------------------------------------------------------
extern "C" void kernel_launch(void* const* d_in, const int* in_sizes, int n_in,
                              void* d_out, int out_size, void* d_ws, size_t ws_size,
                              hipStream_t stream)
{
    (void)in_sizes; (void)n_in; (void)out_size; (void)ws_size;

    const float* left  = (const float*)d_in[0];
    const float* right = (const float*)d_in[1];
    const float* Wq    = (const float*)d_in[2];
    const float* bq    = (const float*)d_in[3];
    const float* Wk    = (const float*)d_in[4];
    const float* bk    = (const float*)d_in[5];
    const int* self_flag = (const int*)d_in[7];
    const int* same_flag = (const int*)d_in[8];

    __half* wsQ = (__half*)d_ws;                       // 32 MiB
    __half* wsK = wsQ + (size_t)B_ * CH * NPX;         // 32 MiB
    float*  WtQ = (float*)(wsK + (size_t)B_ * CH * NPX);
    float*  WtK = WtQ + CH * CIN;

    float* out = (float*)d_out;

    wtrans_kernel<<<1, 256, 0, stream>>>(Wq, Wk, same_flag, WtQ, WtK);

    // Q from left features (always Wq/bq)
    conv_kernel<<<dim3(B_ * 4), 256, 0, stream>>>(left, WtQ, bq, bq, nullptr, wsQ);

    // K from right features; attend-right -> out[:,128:256]
    conv_kernel<<<dim3(B_ * 4), 256, 0, stream>>>(right, WtK, bk, bq, same_flag, wsK);
    attend_kernel<<<dim3(B_ * 2), 256, 0, stream>>>(wsQ, wsK, right, out, CIN, nullptr, self_flag);

    // K from left features; attend-left -> out[:,0:128] (copy if !self_attend)
    conv_kernel<<<dim3(B_ * 4), 256, 0, stream>>>(left, WtK, bk, bq, same_flag, wsK);
    attend_kernel<<<dim3(B_ * 2), 256, 0, stream>>>(wsQ, wsK, left, out, 0, left, self_flag);
}

// Round 3
// 564.578 us; speedup vs baseline: 2.2322x; 2.2322x over previous
//
#include <hip/hip_runtime.h>
#include <hip/hip_fp16.h>

#define B_    256
#define CIN   128
#define CH    64
#define NPX   1024   // 32*32
#define NWIN  49
#define TROWS 22     // 16 tile rows + 3 halo each side
#define TCOLS 40     // 32 cols + 4 halo each side
#define CG    8      // channels per LDS group
#define NEG_INF_F (-1e30f)

// ---------------------------------------------------------------------------
// Transpose W (Ch x Cin -> Cin x Ch); resolve same_WqWk on device.
// ---------------------------------------------------------------------------
__global__ __launch_bounds__(256) void wtrans_kernel(
    const float* __restrict__ Wq, const float* __restrict__ Wk,
    const int* __restrict__ same_flag,
    float* __restrict__ WtQ, float* __restrict__ WtK)
{
    const float* Wsel = (same_flag[0] != 0) ? Wq : Wk;
    for (int idx = threadIdx.x; idx < CH * CIN; idx += 256) {
        int i = idx >> 6;
        int o = idx & 63;
        WtQ[idx] = Wq[o * CIN + i];
        WtK[idx] = Wsel[o * CIN + i];
    }
}

// ---------------------------------------------------------------------------
// 1x1 conv: dst[b,o,p] = sum_i Wt[i,o]*x[b,i,p] + bias[o], output f16.
// (256,2): 128-VGPR cap; live set acc[64]+~15 fits -> no spill.
// ---------------------------------------------------------------------------
__global__ __launch_bounds__(256, 2) void conv_kernel(
    const float* __restrict__ x, const float* __restrict__ Wt,
    const float* __restrict__ bias_a, const float* __restrict__ bias_b,
    const int* __restrict__ sel_flag,
    __half* __restrict__ dst)
{
    const float* bias = (sel_flag != nullptr && sel_flag[0] != 0) ? bias_b : bias_a;
    int b  = blockIdx.x >> 2;
    int px = ((blockIdx.x & 3) << 8) + threadIdx.x;

    const float* xb = x + (size_t)b * (CIN * NPX) + px;
    float acc[CH];
#pragma unroll
    for (int o = 0; o < CH; ++o) acc[o] = bias[o];

#pragma unroll 4
    for (int i = 0; i < CIN; ++i) {
        float xv = xb[(size_t)i * NPX];
        const float* wrow = Wt + (i << 6);
#pragma unroll
        for (int o = 0; o < CH; ++o) acc[o] = fmaf(wrow[o], xv, acc[o]);
    }

    __half* db = dst + (size_t)b * (CH * NPX) + px;
#pragma unroll
    for (int o = 0; o < CH; ++o) db[(size_t)o << 10] = __float2half(acc[o]);
}

// pick half (i) out of a packed __half2 array, i compile-time constant
#define PW(arr, i) __half2float(((i) & 1) ? __high2half(arr[(i) >> 1]) : __low2half(arr[(i) >> 1]))

// One score pass for pixel row (h+P): stages K groups, accumulates sc[49],
// masked softmax, packs weights into PH[25] (__half2). P is a literal 0/1 so
// all indexing is compile-time after unroll; only ONE sc[49] is live at a
// time -> peak live set ~95 VGPRs (fits the 128 cap of launch_bounds(256,2)).
#define A_PASS(P, PH)                                                          \
  {                                                                            \
    const int hp   = h + (P);                                                  \
    const int tapP = ((r2 + (P)) * TCOLS + (w + 1)) * CG;                      \
    float sc[NWIN];                                                            \
    _Pragma("unroll") for (int i = 0; i < NWIN; ++i) sc[i] = 0.f;              \
    for (int cg = 0; cg < CH / CG; ++cg) {                                     \
      __syncthreads();                                                         \
      {                                                                        \
        const __half* Ks = Kb + ((size_t)(cg * CG) << 10);                     \
        int go = go_base, li = li_base;                                        \
        _Pragma("unroll") for (int i2 = 0; i2 < 19; ++i2) {                    \
          buf[li] = Ks[go]; go += 32; li += TCOLS * CG;                        \
        }                                                                      \
      }                                                                        \
      __syncthreads();                                                         \
      float qa[CG];                                                            \
      _Pragma("unroll") for (int c = 0; c < CG; ++c)                           \
        qa[c] = __half2float(Qb[(((size_t)(cg * CG + c)) << 10) + (hp << 5) + w]); \
      _Pragma("unroll") for (int dh = 0; dh < 7; ++dh) {                       \
        _Pragma("unroll") for (int dw = 0; dw < 7; ++dw) {                     \
          union { int4 v; __half hh[8]; } kk;                                  \
          kk.v = *(const int4*)(buf + tapP + (dh * TCOLS + dw) * CG);          \
          float s = sc[dh * 7 + dw];                                           \
          _Pragma("unroll") for (int c = 0; c < CG; ++c)                       \
            s = fmaf(__half2float(kk.hh[c]), qa[c], s);                        \
          sc[dh * 7 + dw] = s;                                                 \
        }                                                                      \
      }                                                                        \
    }                                                                          \
    float m = NEG_INF_F;                                                       \
    _Pragma("unroll") for (int dh = 0; dh < 7; ++dh) {                         \
      _Pragma("unroll") for (int dw = 0; dw < 7; ++dw) {                       \
        int i = dh * 7 + dw;                                                   \
        bool vld = ((unsigned)(hp + dh - 3) < 32u) &&                          \
                   ((unsigned)(w + dw - 3) < 32u);                             \
        sc[i] = vld ? sc[i] : NEG_INF_F;                                       \
        m = fmaxf(m, sc[i]);                                                   \
      }                                                                        \
    }                                                                          \
    float ssum = 0.f;                                                          \
    _Pragma("unroll") for (int i = 0; i < NWIN; ++i) {                         \
      sc[i] = __expf(sc[i] - m); ssum += sc[i];                                \
    }                                                                          \
    float inv = 1.f / ssum;                                                    \
    _Pragma("unroll") for (int j = 0; j < 24; ++j)                             \
      PH[j] = __halves2half2(__float2half(sc[2 * j] * inv),                    \
                             __float2half(sc[2 * j + 1] * inv));               \
    PH[24] = __halves2half2(__float2half(sc[48] * inv), __float2half(0.f));    \
  }

// ---------------------------------------------------------------------------
// Fused local attention, 16-row tile per block, 2 vertical px per thread.
// LDS tile [22 rows][40 cols][8 ch] f16 (14 KB), zero borders filled once.
// Phase A: TWO sequential score passes (one sc[49] live at a time).
// Phase C: shared window-row taps serve both pixels (1.75x byte reduction).
// ---------------------------------------------------------------------------
__global__ __launch_bounds__(256, 2) void attend_kernel(
    const __half* __restrict__ Q, const __half* __restrict__ K,
    const float* __restrict__ V,          // raw key-side features, CIN ch
    float* __restrict__ out,              // (B,256,32,32) f32
    int chan_base,
    const float* __restrict__ copy_src,   // left features (self_attend==0)
    const int* __restrict__ self_flag)
{
    __shared__ __align__(16) __half buf[TROWS * TCOLS * CG];   // 14080 B

    int b    = blockIdx.x >> 1;
    int h0   = (blockIdx.x & 1) << 4;
    int t    = threadIdx.x;
    int w    = t & 31;
    int r2   = (t >> 5) << 1;     // 0,2,..,14
    int h    = h0 + r2;           // this thread: rows h and h+1

    if (copy_src != nullptr && self_flag[0] == 0) {
        const float* s = copy_src + (size_t)b * (CIN * NPX) + (h << 5) + w;
        float* d = out + (size_t)b * (2 * CIN * NPX) + ((size_t)chan_base << 10) + (h << 5) + w;
        for (int c = 0; c < CIN; ++c) {
            d[(size_t)c << 10] = s[(size_t)c << 10];
            d[((size_t)c << 10) + 32] = s[((size_t)c << 10) + 32];
        }
        return;
    }

    // ---- zero-fill LDS once (borders stay 0 across all groups/passes) ----
    int* ibuf = (int*)buf;
#pragma unroll
    for (int i = 0; i < 14; ++i) {
        int idx = t + (i << 8);
        if (idx < TROWS * TCOLS * CG / 2) ibuf[idx] = 0;
    }

    // ---- staging geometry (shift-only; no divisions) ----
    // 19 valid rows x 32 cols x 8 ch = 4864 elems = 256 thr x 19 iters.
    int rowlo = (h0 == 0) ? 0 : h0 - 3;       // first valid global row
    int rowof = (h0 == 0) ? 3 : 0;            // its LDS row index
    int sc_c  = (t >> 5) & 7;                 // this thread's staging channel
    int go_base = (sc_c << 10) + (rowlo << 5) + w;
    int li_base = (rowof * TCOLS + w + 4) * CG + sc_c;

    const __half* Kb = K + (size_t)b * (CH * NPX);
    const __half* Qb = Q + (size_t)b * (CH * NPX);
    int qoff = (h << 5) + w;

    // ---- Phase A: two sequential passes (px row h, then h+1) ----
    __half2 ph0[25], ph1[25];
    A_PASS(0, ph0)
    A_PASS(1, ph1)

    // ---- Phase C: weighted V sum, 8 channels per group, taps shared ----
    const float* Vb = V + (size_t)b * (CIN * NPX);
    float* ob = out + (size_t)b * (2 * CIN * NPX) + ((size_t)chan_base << 10) + qoff;
    int tap0 = (r2 * TCOLS + (w + 1)) * CG;   // window row 0 for px0

    for (int vg = 0; vg < CIN / CG; ++vg) {
        __syncthreads();
        {
            const float* Vs = Vb + ((size_t)(vg * CG) << 10);
            int go = go_base, li = li_base;
#pragma unroll
            for (int i = 0; i < 19; ++i) {
                buf[li] = __float2half(Vs[go]);
                go += 32; li += TCOLS * CG;
            }
        }
        __syncthreads();

        float a0[CG], a1[CG];
#pragma unroll
        for (int c = 0; c < CG; ++c) { a0[c] = 0.f; a1[c] = 0.f; }
#pragma unroll
        for (int wr = 0; wr < 8; ++wr) {
#pragma unroll
            for (int dw = 0; dw < 7; ++dw) {
                union { int4 v; __half hh[8]; } vv;
                vv.v = *(const int4*)(buf + tap0 + (wr * TCOLS + dw) * CG);
                if (wr < 7) {
                    float p = PW(ph0, wr * 7 + dw);
#pragma unroll
                    for (int c = 0; c < CG; ++c) a0[c] = fmaf(__half2float(vv.hh[c]), p, a0[c]);
                }
                if (wr >= 1) {
                    float p = PW(ph1, (wr - 1) * 7 + dw);
#pragma unroll
                    for (int c = 0; c < CG; ++c) a1[c] = fmaf(__half2float(vv.hh[c]), p, a1[c]);
                }
            }
        }
#pragma unroll
        for (int c = 0; c < CG; ++c) {
            ob[((size_t)(vg * CG + c)) << 10] = a0[c];
            ob[(((size_t)(vg * CG + c)) << 10) + 32] = a1[c];
        }
    }
}

// ---------------------------------------------------------------------------
// Order: both left-reading convs run back-to-back (left stays L2/L3-hot).
// ws: 3 x 32 MiB f16 (Q, K_right, K_left) + 2 W transposes = 96.06 MiB.
// ---------------------------------------------------------------------------
extern "C" void kernel_launch(void* const* d_in, const int* in_sizes, int n_in,
                              void* d_out, int out_size, void* d_ws, size_t ws_size,
                              hipStream_t stream)
{
    (void)in_sizes; (void)n_in; (void)out_size; (void)ws_size;

    const float* left  = (const float*)d_in[0];
    const float* right = (const float*)d_in[1];
    const float* Wq    = (const float*)d_in[2];
    const float* bq    = (const float*)d_in[3];
    const float* Wk    = (const float*)d_in[4];
    const float* bk    = (const float*)d_in[5];
    const int* self_flag = (const int*)d_in[7];
    const int* same_flag = (const int*)d_in[8];

    __half* wsQ  = (__half*)d_ws;                        // 32 MiB
    __half* wsKR = wsQ  + (size_t)B_ * CH * NPX;         // 32 MiB
    __half* wsKL = wsKR + (size_t)B_ * CH * NPX;         // 32 MiB
    float*  WtQ  = (float*)(wsKL + (size_t)B_ * CH * NPX);
    float*  WtK  = WtQ + CH * CIN;

    float* out = (float*)d_out;

    wtrans_kernel<<<1, 256, 0, stream>>>(Wq, Wk, same_flag, WtQ, WtK);

    // Both left-reading convs adjacent (cache reuse), then right.
    conv_kernel<<<dim3(B_ * 4), 256, 0, stream>>>(left,  WtQ, bq, bq, nullptr,   wsQ);
    conv_kernel<<<dim3(B_ * 4), 256, 0, stream>>>(left,  WtK, bk, bq, same_flag, wsKL);
    conv_kernel<<<dim3(B_ * 4), 256, 0, stream>>>(right, WtK, bk, bq, same_flag, wsKR);

    // attend-right -> out[:,128:256]
    attend_kernel<<<dim3(B_ * 2), 256, 0, stream>>>(wsQ, wsKR, right, out, CIN, nullptr, self_flag);
    // attend-left -> out[:,0:128] (copy path if self_attend==0)
    attend_kernel<<<dim3(B_ * 2), 256, 0, stream>>>(wsQ, wsKL, left,  out, 0,    left,    self_flag);
}

// Round 5
// 398.908 us; speedup vs baseline: 3.1593x; 1.4153x over previous
//
#include <hip/hip_runtime.h>
#include <hip/hip_fp16.h>

#define B_    256
#define CIN   128
#define CH    64
#define NPX   1024   // 32*32
#define NWIN  49
#define TROWS 22     // 16 tile rows + 3 halo each side
#define TCOLS 40     // 32 cols + 4 halo each side
#define NEG_INF_F (-1e30f)

typedef _Float16 h2v __attribute__((ext_vector_type(2)));
typedef __fp16   p2v __attribute__((ext_vector_type(2)));   // cvt_pkrtz result type

#if __has_builtin(__builtin_amdgcn_fdot2)
#define FDOT2(a, b, c) __builtin_amdgcn_fdot2((a), (b), (c), false)
#else
#define FDOT2(a, b, c) fmaf((float)(a)[0], (float)(b)[0], fmaf((float)(a)[1], (float)(b)[1], (c)))
#endif

union U2 { uint u[2]; h2v h[2]; };
union CV { p2v p; h2v h; uint u; };

// acc(f32) += f16(vu, half vh) * f16(pu, half ph) — one v_fma_mix_f32.
// vh/ph are literal after unroll -> dead branches fold.
#define FMIX(acc, vu, vh, pu, ph) do {                                                                              \
    if      ((vh) == 0 && (ph) == 0) asm("v_fma_mix_f32 %0, %1, %2, %0 op_sel:[0,0,0] op_sel_hi:[1,1,0]" : "+v"(acc) : "v"(vu), "v"(pu)); \
    else if ((vh) == 1 && (ph) == 0) asm("v_fma_mix_f32 %0, %1, %2, %0 op_sel:[1,0,0] op_sel_hi:[1,1,0]" : "+v"(acc) : "v"(vu), "v"(pu)); \
    else if ((vh) == 0 && (ph) == 1) asm("v_fma_mix_f32 %0, %1, %2, %0 op_sel:[0,1,0] op_sel_hi:[1,1,0]" : "+v"(acc) : "v"(vu), "v"(pu)); \
    else                             asm("v_fma_mix_f32 %0, %1, %2, %0 op_sel:[1,1,0] op_sel_hi:[1,1,0]" : "+v"(acc) : "v"(vu), "v"(pu)); \
} while (0)

// ---------------------------------------------------------------------------
__global__ __launch_bounds__(256) void wtrans_kernel(
    const float* __restrict__ Wq, const float* __restrict__ Wk,
    const int* __restrict__ same_flag,
    float* __restrict__ WtQ, float* __restrict__ WtK)
{
    const float* Wsel = (same_flag[0] != 0) ? Wq : Wk;
    for (int idx = threadIdx.x; idx < CH * CIN; idx += 256) {
        int i = idx >> 6;
        int o = idx & 63;
        WtQ[idx] = Wq[o * CIN + i];
        WtK[idx] = Wsel[o * CIN + i];
    }
}

// ---------------------------------------------------------------------------
// All three 1x1 convs in one launch (blockIdx.y = 0:Q(left) 1:K(left) 2:K(right)).
// Output layout: channel-PAIR interleaved uints: dst[(o/2)<<10 | px] = {f16(acc[o]),f16(acc[o+1])}
// so the attend kernel's fdot2 operands are direct 4B loads.
// ---------------------------------------------------------------------------
__global__ __launch_bounds__(256, 4) void conv3_kernel(
    const float* __restrict__ left, const float* __restrict__ right,
    const float* __restrict__ WtQ, const float* __restrict__ WtK,
    const float* __restrict__ bq, const float* __restrict__ bk,
    const int* __restrict__ same_flag,
    uint* __restrict__ dQ, uint* __restrict__ dKL, uint* __restrict__ dKR)
{
    int which = blockIdx.y;
    const float* x    = (which == 2) ? right : left;
    const float* Wt   = (which == 0) ? WtQ : WtK;
    const float* bias = (which == 0 || same_flag[0] != 0) ? bq : bk;
    uint* dst         = (which == 0) ? dQ : ((which == 1) ? dKL : dKR);

    int b  = blockIdx.x >> 2;
    int px = ((blockIdx.x & 3) << 8) + threadIdx.x;

    const float* xb = x + (size_t)b * (CIN * NPX) + px;
    float acc[CH];
#pragma unroll
    for (int o = 0; o < CH; ++o) acc[o] = bias[o];

#pragma unroll 4
    for (int i = 0; i < CIN; ++i) {
        float xv = xb[(size_t)i * NPX];
        const float* wrow = Wt + (i << 6);
#pragma unroll
        for (int o = 0; o < CH; ++o) acc[o] = fmaf(wrow[o], xv, acc[o]);
    }

    uint* db = dst + (size_t)b * ((CH / 2) * NPX) + px;
#pragma unroll
    for (int o2 = 0; o2 < CH / 2; ++o2) {
        CV cv; cv.p = __builtin_amdgcn_cvt_pkrtz(acc[2 * o2], acc[2 * o2 + 1]);
        db[(size_t)o2 << 10] = cv.u;
    }
}

// ---------------------------------------------------------------------------
// Merged fused local attention: blockIdx.y = 0 (Q_left x K_right/V_right ->
// out[:,128:256]) or 1 (Q_left x K_left/V_left -> out[:,0:128]; copy path if
// self_attend==0). 16-row tile, 2 vertical px/thread, taps shared in BOTH
// phases. Phase A: K LDS [22][40][4ch] f16 (b64 taps), fdot2 MACs.
// Phase C: V LDS [22][40][8ch] f16 (b128 taps), v_fma_mix MACs (f16 p).
// ---------------------------------------------------------------------------
__global__ __launch_bounds__(256, 4) void attend2_kernel(
    const uint* __restrict__ Q, const uint* __restrict__ KR,
    const uint* __restrict__ KL,
    const float* __restrict__ right, const float* __restrict__ left,
    float* __restrict__ out, const int* __restrict__ self_flag)
{
    __shared__ __align__(16) __half buf[TROWS * TCOLS * 8];   // 14080 B

    int side = blockIdx.y;            // 0: right-attend, 1: left-attend
    int b    = blockIdx.x >> 1;
    int h0   = (blockIdx.x & 1) << 4;
    int t    = threadIdx.x;
    int w    = t & 31;
    int r2   = (t >> 5) << 1;         // 0,2,..,14
    int h    = h0 + r2;               // rows h and h+1
    int qoff = (h << 5) + w;
    int cb   = side ? 0 : CIN;

    const uint*  K = side ? KL : KR;
    const float* V = side ? left : right;

    if (side == 1 && self_flag[0] == 0) {
        const float* s = left + (size_t)b * (CIN * NPX) + qoff;
        float* d = out + (size_t)b * (2 * CIN * NPX) + qoff;
        for (int c = 0; c < CIN; ++c) {
            d[(size_t)c << 10] = s[(size_t)c << 10];
            d[((size_t)c << 10) + 32] = s[((size_t)c << 10) + 32];
        }
        return;
    }

    // ---- zero phase-A region: [22][40][4] f16 = 7040 B = 1760 ints ----
    int* ibuf = (int*)buf;
#pragma unroll
    for (int i = 0; i < 7; ++i) {
        int idx = t + (i << 8);
        if (idx < 1760) ibuf[idx] = 0;
    }

    int rowlo = (h0 == 0) ? 0 : h0 - 3;   // first valid global row (19 staged)
    int rowof = (h0 == 0) ? 3 : 0;        // its LDS row

    int kpA = (t >> 5) & 1;   // A staging: channel-pair within group
    int r4A = t >> 6;         // A staging: row mod 4 (wave-uniform)
    int vpC = (t >> 5) & 3;   // C staging: channel-pair within group
    int r2C = t >> 7;         // C staging: row parity (wave-uniform)

    const uint* Kb = K + (size_t)b * ((CH / 2) * NPX);
    const uint* Qb = Q + (size_t)b * ((CH / 2) * NPX);

    float sc0[NWIN], sc1[NWIN];
#pragma unroll
    for (int i = 0; i < NWIN; ++i) { sc0[i] = 0.f; sc1[i] = 0.f; }

    // ---- Phase A: 16 groups of 4 channels; taps shared between px0/px1 ----
    for (int g = 0; g < 16; ++g) {
        __syncthreads();
        {
            const uint* Ks = Kb + ((size_t)(2 * g + kpA) << 10);
#pragma unroll
            for (int i = 0; i < 5; ++i) {
                int row = (i << 2) + r4A;
                if (row < 19)
                    *((uint*)buf + ((((rowof + row) * TCOLS + (w + 4)) << 1) + kpA)) =
                        Ks[((rowlo + row) << 5) + w];
            }
        }
        __syncthreads();

        U2 qa, qc;
        qa.u[0] = Qb[((size_t)(2 * g) << 10) + qoff];
        qa.u[1] = Qb[((size_t)(2 * g + 1) << 10) + qoff];
        qc.u[0] = Qb[((size_t)(2 * g) << 10) + qoff + 32];
        qc.u[1] = Qb[((size_t)(2 * g + 1) << 10) + qoff + 32];

        const U2* cells = (const U2*)buf;
#pragma unroll
        for (int dh = 0; dh < 8; ++dh) {
#pragma unroll
            for (int dw = 0; dw < 7; ++dw) {
                U2 kk = cells[(r2 + dh) * TCOLS + (w + 1 + dw)];
                if (dh < 7) {
                    float s = sc0[dh * 7 + dw];
                    s = FDOT2(kk.h[0], qa.h[0], s);
                    s = FDOT2(kk.h[1], qa.h[1], s);
                    sc0[dh * 7 + dw] = s;
                }
                if (dh >= 1) {
                    float s = sc1[(dh - 1) * 7 + dw];
                    s = FDOT2(kk.h[0], qc.h[0], s);
                    s = FDOT2(kk.h[1], qc.h[1], s);
                    sc1[(dh - 1) * 7 + dw] = s;
                }
            }
        }
    }

    // ---- softmax per pixel; weights packed to f16 pairs (register relief) ----
    uint ph0[25], ph1[25];
    {
        float m = NEG_INF_F;
#pragma unroll
        for (int dh = 0; dh < 7; ++dh)
#pragma unroll
            for (int dw = 0; dw < 7; ++dw) {
                int i = dh * 7 + dw;
                bool vld = ((unsigned)(h + dh - 3) < 32u) && ((unsigned)(w + dw - 3) < 32u);
                sc0[i] = vld ? sc0[i] : NEG_INF_F;
                m = fmaxf(m, sc0[i]);
            }
        float ssum = 0.f;
#pragma unroll
        for (int i = 0; i < NWIN; ++i) { sc0[i] = __expf(sc0[i] - m); ssum += sc0[i]; }
        float inv = 1.f / ssum;
#pragma unroll
        for (int j = 0; j < 24; ++j) {
            CV cv; cv.p = __builtin_amdgcn_cvt_pkrtz(sc0[2 * j] * inv, sc0[2 * j + 1] * inv);
            ph0[j] = cv.u;
        }
        CV cv; cv.p = __builtin_amdgcn_cvt_pkrtz(sc0[48] * inv, 0.f);
        ph0[24] = cv.u;
    }
    {
        float m = NEG_INF_F;
#pragma unroll
        for (int dh = 0; dh < 7; ++dh)
#pragma unroll
            for (int dw = 0; dw < 7; ++dw) {
                int i = dh * 7 + dw;
                bool vld = ((unsigned)(h + 1 + dh - 3) < 32u) && ((unsigned)(w + dw - 3) < 32u);
                sc1[i] = vld ? sc1[i] : NEG_INF_F;
                m = fmaxf(m, sc1[i]);
            }
        float ssum = 0.f;
#pragma unroll
        for (int i = 0; i < NWIN; ++i) { sc1[i] = __expf(sc1[i] - m); ssum += sc1[i]; }
        float inv = 1.f / ssum;
#pragma unroll
        for (int j = 0; j < 24; ++j) {
            CV cv; cv.p = __builtin_amdgcn_cvt_pkrtz(sc1[2 * j] * inv, sc1[2 * j + 1] * inv);
            ph1[j] = cv.u;
        }
        CV cv; cv.p = __builtin_amdgcn_cvt_pkrtz(sc1[48] * inv, 0.f);
        ph1[24] = cv.u;
    }

    // ---- re-zero full buffer for phase-C layout [22][40][8] f16 ----
    __syncthreads();   // all phase-A tap reads complete
#pragma unroll
    for (int i = 0; i < 14; ++i) {
        int idx = t + (i << 8);
        if (idx < 3520) ibuf[idx] = 0;
    }
    // first C-iteration barrier orders zero-fill vs staging

    const float* Vb = V + (size_t)b * (CIN * NPX);
    float* ob = out + (size_t)b * (2 * CIN * NPX) + ((size_t)cb << 10) + qoff;

    for (int vg = 0; vg < 16; ++vg) {
        __syncthreads();
        {
            int c0 = (vg << 3) + (vpC << 1);
            const float* va = Vb + ((size_t)c0 << 10);
            const float* vc = va + NPX;
#pragma unroll
            for (int i = 0; i < 10; ++i) {
                int row = (i << 1) + r2C;
                if (row < 19) {
                    int gi = ((rowlo + row) << 5) + w;
                    CV cv; cv.p = __builtin_amdgcn_cvt_pkrtz(va[gi], vc[gi]);
                    *((uint*)buf + ((((rowof + row) * TCOLS + (w + 4)) << 2) + vpC)) = cv.u;
                }
            }
        }
        __syncthreads();

        float a0[8], a1[8];
#pragma unroll
        for (int c = 0; c < 8; ++c) { a0[c] = 0.f; a1[c] = 0.f; }

        const int4* cell4 = (const int4*)buf;
#pragma unroll
        for (int dh = 0; dh < 8; ++dh) {
#pragma unroll
            for (int dw = 0; dw < 7; ++dw) {
                union { int4 v; uint u[4]; } kk;
                kk.v = cell4[(r2 + dh) * TCOLS + (w + 1 + dw)];
                if (dh < 7) {
                    int tp = dh * 7 + dw;
#pragma unroll
                    for (int c = 0; c < 8; ++c)
                        FMIX(a0[c], kk.u[c >> 1], (c & 1), ph0[tp >> 1], (tp & 1));
                }
                if (dh >= 1) {
                    int tp = (dh - 1) * 7 + dw;
#pragma unroll
                    for (int c = 0; c < 8; ++c)
                        FMIX(a1[c], kk.u[c >> 1], (c & 1), ph1[tp >> 1], (tp & 1));
                }
            }
        }
#pragma unroll
        for (int c = 0; c < 8; ++c) {
            ob[((size_t)((vg << 3) + c)) << 10] = a0[c];
            ob[(((size_t)((vg << 3) + c)) << 10) + 32] = a1[c];
        }
    }
}

// ---------------------------------------------------------------------------
// 3 launches total: wtrans -> conv3 (3072 blocks) -> attend2 (1024 blocks).
// ws: 3 x 32 MiB pair-packed f16 (Q, K_left, K_right) + 2 W transposes.
// ---------------------------------------------------------------------------
extern "C" void kernel_launch(void* const* d_in, const int* in_sizes, int n_in,
                              void* d_out, int out_size, void* d_ws, size_t ws_size,
                              hipStream_t stream)
{
    (void)in_sizes; (void)n_in; (void)out_size; (void)ws_size;

    const float* left  = (const float*)d_in[0];
    const float* right = (const float*)d_in[1];
    const float* Wq    = (const float*)d_in[2];
    const float* bq    = (const float*)d_in[3];
    const float* Wk    = (const float*)d_in[4];
    const float* bk    = (const float*)d_in[5];
    const int* self_flag = (const int*)d_in[7];
    const int* same_flag = (const int*)d_in[8];

    uint* wsQ  = (uint*)d_ws;                              // 32 MiB
    uint* wsKL = wsQ  + (size_t)B_ * (CH / 2) * NPX;       // 32 MiB
    uint* wsKR = wsKL + (size_t)B_ * (CH / 2) * NPX;       // 32 MiB
    float* WtQ = (float*)(wsKR + (size_t)B_ * (CH / 2) * NPX);
    float* WtK = WtQ + CH * CIN;

    float* out = (float*)d_out;

    wtrans_kernel<<<1, 256, 0, stream>>>(Wq, Wk, same_flag, WtQ, WtK);

    conv3_kernel<<<dim3(B_ * 4, 3), 256, 0, stream>>>(
        left, right, WtQ, WtK, bq, bk, same_flag, wsQ, wsKL, wsKR);

    attend2_kernel<<<dim3(B_ * 2, 2), 256, 0, stream>>>(
        wsQ, wsKR, wsKL, right, left, out, self_flag);
}